// Round 1
// baseline (13828.206 us; speedup 1.0000x reference)
//
#include <hip/hip_runtime.h>

#define NN 500000      // nodes
#define NE 16000000    // edges
#define HD 32          // hidden
#define NMID 6
#define F0 3

static constexpr float ALPHA = 0.9f;
static constexpr float OMA = 1.0f - 0.9f; // 0.1

// ---------------------------------------------------------------------------
// Precompute combined residual weights: wc_mid[i] = 0.1 * (w_init_mid[i] @ w_x_mid[i])  [3,32]
//                                       wc_last   = 0.1 * (w_init_last @ w_x_last)      [3,1]
__global__ void prep_weights(const float* __restrict__ w_init_mid,
                             const float* __restrict__ w_x_mid,
                             const float* __restrict__ w_init_last,
                             const float* __restrict__ w_x_last,
                             float* __restrict__ wc_mid,
                             float* __restrict__ wc_last) {
    int t = threadIdx.x;
    if (t < NMID * F0 * HD) {
        int i = t / (F0 * HD);
        int r = t - i * (F0 * HD);
        int k = r / HD, f = r % HD;
        const float* wi = w_init_mid + (size_t)i * F0 * HD; // [3,32]
        const float* wx = w_x_mid + (size_t)i * HD * HD;    // [32,32]
        float acc = 0.f;
        for (int j = 0; j < HD; ++j) acc += wi[k * HD + j] * wx[j * HD + f];
        wc_mid[t] = OMA * acc;
    } else if (t < NMID * F0 * HD + F0) {
        int k = t - NMID * F0 * HD;
        float acc = 0.f;
        for (int j = 0; j < HD; ++j) acc += w_init_last[k * HD + j] * w_x_last[j];
        wc_last[k] = OMA * acc;
    }
}

// ---------------------------------------------------------------------------
// Layer 1: agg3 = A @ x  (F=3), thread per edge
__global__ void spmm_f3(const int* __restrict__ rows, const int* __restrict__ cols,
                        const float* __restrict__ vals, const float* __restrict__ x,
                        float* __restrict__ agg3) {
    int e = blockIdx.x * blockDim.x + threadIdx.x;
    if (e >= NE) return;
    int r = rows[e], c = cols[e];
    float v = vals[e];
    atomicAdd(&agg3[r * 3 + 0], v * x[c * 3 + 0]);
    atomicAdd(&agg3[r * 3 + 1], v * x[c * 3 + 1]);
    atomicAdd(&agg3[r * 3 + 2], v * x[c * 3 + 2]);
}

// Layer 1 epilogue: blend3 = 0.9*agg3 + 0.1*(x0 @ w_init0); h = relu(blend3 @ w_x0);
// g_out = h @ (0.9 * w_x_mid[0])   — 32 lanes per node, shuffle matvec.
__global__ void epilogue1(const float* __restrict__ agg3, const float* __restrict__ x0,
                          const float* __restrict__ w_init0, const float* __restrict__ w_x0,
                          const float* __restrict__ w_x_next, float* __restrict__ g_out) {
    int tid = blockIdx.x * blockDim.x + threadIdx.x;
    int n = tid >> 5, f = tid & 31;
    if (n >= NN) return;
    float a0 = agg3[n * 3 + 0], a1 = agg3[n * 3 + 1], a2 = agg3[n * 3 + 2];
    float p0 = x0[n * 3 + 0], p1 = x0[n * 3 + 1], p2 = x0[n * 3 + 2];
    float b0 = ALPHA * a0 + OMA * (p0 * w_init0[0] + p1 * w_init0[3] + p2 * w_init0[6]);
    float b1 = ALPHA * a1 + OMA * (p0 * w_init0[1] + p1 * w_init0[4] + p2 * w_init0[7]);
    float b2 = ALPHA * a2 + OMA * (p0 * w_init0[2] + p1 * w_init0[5] + p2 * w_init0[8]);
    float h = fmaxf(b0 * w_x0[0 * HD + f] + b1 * w_x0[1 * HD + f] + b2 * w_x0[2 * HD + f], 0.f);
    float acc = 0.f;
    #pragma unroll
    for (int k = 0; k < HD; ++k) {
        float hk = __shfl(h, k, 32);
        acc += hk * w_x_next[k * HD + f];
    }
    g_out[n * HD + f] = ALPHA * acc;
}

// ---------------------------------------------------------------------------
// Mid layers: seed agg with residual term 0.1*(x0 @ Wi @ Wx)   (replaces memset)
__global__ void seed_mid(const float* __restrict__ x0, const float* __restrict__ wc,
                         float* __restrict__ agg) {
    int tid = blockIdx.x * blockDim.x + threadIdx.x;
    int n = tid >> 5, f = tid & 31;
    if (n >= NN) return;
    agg[n * HD + f] = x0[n * 3 + 0] * wc[0 * HD + f]
                    + x0[n * 3 + 1] * wc[1 * HD + f]
                    + x0[n * 3 + 2] * wc[2 * HD + f];
}

// SpMM F=32: 32 lanes per edge, coalesced gather + coalesced atomics
__global__ void spmm_f32(const int* __restrict__ rows, const int* __restrict__ cols,
                         const float* __restrict__ vals, const float* __restrict__ g,
                         float* __restrict__ agg) {
    int tid = blockIdx.x * blockDim.x + threadIdx.x;
    int e = tid >> 5, f = tid & 31;
    if (e >= NE) return;
    int r = rows[e], c = cols[e];
    float v = vals[e];
    atomicAdd(&agg[r * HD + f], v * g[c * HD + f]);
}

// Mid epilogue: h = relu(agg); g_out = h @ (0.9 * w_x_next)
__global__ void epilogue_mid(const float* __restrict__ agg,
                             const float* __restrict__ w_x_next,
                             float* __restrict__ g_out) {
    int tid = blockIdx.x * blockDim.x + threadIdx.x;
    int n = tid >> 5, f = tid & 31;
    if (n >= NN) return;
    float h = fmaxf(agg[n * HD + f], 0.f);
    float acc = 0.f;
    #pragma unroll
    for (int k = 0; k < HD; ++k) {
        float hk = __shfl(h, k, 32);
        acc += hk * w_x_next[k * HD + f];
    }
    g_out[n * HD + f] = ALPHA * acc;
}

// Epilogue of last mid layer: h = relu(agg); g1 = h @ (0.9 * w_x_last)  -> [N,1]
__global__ void epilogue_to1(const float* __restrict__ agg,
                             const float* __restrict__ w_x_last,
                             float* __restrict__ g1) {
    int tid = blockIdx.x * blockDim.x + threadIdx.x;
    int n = tid >> 5, f = tid & 31;
    if (n >= NN) return;
    float v = fmaxf(agg[n * HD + f], 0.f) * w_x_last[f];
    #pragma unroll
    for (int m = 16; m >= 1; m >>= 1) v += __shfl_xor(v, m, 32);
    if (f == 0) g1[n] = ALPHA * v;
}

// ---------------------------------------------------------------------------
// Last layer: seed scalar residual, SpMM F=1, sigmoid
__global__ void seed_last(const float* __restrict__ x0, const float* __restrict__ wcL,
                          float* __restrict__ aggL) {
    int n = blockIdx.x * blockDim.x + threadIdx.x;
    if (n >= NN) return;
    aggL[n] = x0[n * 3 + 0] * wcL[0] + x0[n * 3 + 1] * wcL[1] + x0[n * 3 + 2] * wcL[2];
}

__global__ void spmm_f1(const int* __restrict__ rows, const int* __restrict__ cols,
                        const float* __restrict__ vals, const float* __restrict__ g1,
                        float* __restrict__ aggL) {
    int e = blockIdx.x * blockDim.x + threadIdx.x;
    if (e >= NE) return;
    atomicAdd(&aggL[rows[e]], vals[e] * g1[cols[e]]);
}

__global__ void final_sigmoid(const float* __restrict__ aggL, float* __restrict__ out) {
    int n = blockIdx.x * blockDim.x + threadIdx.x;
    if (n >= NN) return;
    out[n] = 1.f / (1.f + __expf(-aggL[n]));
}

// ---------------------------------------------------------------------------
extern "C" void kernel_launch(void* const* d_in, const int* in_sizes, int n_in,
                              void* d_out, int out_size, void* d_ws, size_t ws_size,
                              hipStream_t stream) {
    const float* x          = (const float*)d_in[0];
    const int*   rows       = (const int*)d_in[1];
    const int*   cols       = (const int*)d_in[2];
    const float* vals       = (const float*)d_in[3];
    const float* w_init0    = (const float*)d_in[4];
    const float* w_x0       = (const float*)d_in[5];
    const float* w_init_mid = (const float*)d_in[6];
    const float* w_x_mid    = (const float*)d_in[7];
    const float* w_init_last= (const float*)d_in[8];
    const float* w_x_last   = (const float*)d_in[9];
    float* out = (float*)d_out;

    char* ws = (char*)d_ws;
    const size_t NH = (size_t)NN * HD * sizeof(float); // 64 MB
    float* g      = (float*)ws;            // [N,32] spmm input
    float* agg    = (float*)(ws + NH);     // [N,32] accumulator (also agg3 / aggL)
    float* wc_mid = (float*)(ws + 2 * NH); // [6,3,32]
    float* wc_last= wc_mid + NMID * F0 * HD;

    const int B = 256;
    const int gridE   = (NE + B - 1) / B;            // thread per edge
    const int gridE32 = (int)(((size_t)NE * 32) / B); // 32 lanes per edge (exact)
    const int gridN32 = (NN * 32 + B - 1) / B;       // 32 lanes per node
    const int gridN   = (NN + B - 1) / B;

    prep_weights<<<1, 1024, 0, stream>>>(w_init_mid, w_x_mid, w_init_last, w_x_last,
                                         wc_mid, wc_last);

    // ---- layer 1 (F=3 spmm in original form) ----
    hipMemsetAsync(agg, 0, (size_t)NN * 3 * sizeof(float), stream);
    spmm_f3<<<gridE, B, 0, stream>>>(rows, cols, vals, x, agg);
    epilogue1<<<gridN32, B, 0, stream>>>(agg, x, w_init0, w_x0, w_x_mid /* layer 0 */, g);

    // ---- mid layers ----
    for (int i = 0; i < NMID; ++i) {
        seed_mid<<<gridN32, B, 0, stream>>>(x, wc_mid + i * F0 * HD, agg);
        spmm_f32<<<gridE32, B, 0, stream>>>(rows, cols, vals, g, agg);
        if (i < NMID - 1)
            epilogue_mid<<<gridN32, B, 0, stream>>>(agg, w_x_mid + (size_t)(i + 1) * HD * HD, g);
        else
            epilogue_to1<<<gridN32, B, 0, stream>>>(agg, w_x_last, g); // g now [N,1]
    }

    // ---- last layer (F=1 spmm thanks to associativity) ----
    seed_last<<<gridN, B, 0, stream>>>(x, wc_last, agg);
    spmm_f1<<<gridE, B, 0, stream>>>(rows, cols, vals, g, agg);
    final_sigmoid<<<gridN, B, 0, stream>>>(agg, out);
}

// Round 2
// 4628.210 us; speedup vs baseline: 2.9878x; 2.9878x over previous
//
#include <hip/hip_runtime.h>

#define NN 500000      // nodes
#define NE 16000000    // edges
#define HD 32          // hidden
#define NMID 6
#define F0 3
#define SCAN_B 1024
#define NB ((NN + SCAN_B - 1) / SCAN_B)   // 489

static constexpr float ALPHA = 0.9f;
static constexpr float OMA = 1.0f - 0.9f; // 0.1

// ---------------------------------------------------------------------------
// wc_mid[i] = 0.1 * (w_init_mid[i] @ w_x_mid[i])  [3,32];  wc_last = 0.1*(Wi_L @ Wx_L) [3]
__global__ void prep_weights(const float* __restrict__ w_init_mid,
                             const float* __restrict__ w_x_mid,
                             const float* __restrict__ w_init_last,
                             const float* __restrict__ w_x_last,
                             float* __restrict__ wc_mid,
                             float* __restrict__ wc_last) {
    int t = threadIdx.x;
    if (t < NMID * F0 * HD) {
        int i = t / (F0 * HD);
        int r = t - i * (F0 * HD);
        int k = r / HD, f = r % HD;
        const float* wi = w_init_mid + (size_t)i * F0 * HD;
        const float* wx = w_x_mid + (size_t)i * HD * HD;
        float acc = 0.f;
        for (int j = 0; j < HD; ++j) acc += wi[k * HD + j] * wx[j * HD + f];
        wc_mid[t] = OMA * acc;
    } else if (t < NMID * F0 * HD + F0) {
        int k = t - NMID * F0 * HD;
        float acc = 0.f;
        for (int j = 0; j < HD; ++j) acc += w_init_last[k * HD + j] * w_x_last[j];
        wc_last[k] = OMA * acc;
    }
}

// ---------------------------------------------------------------------------
// CSR build: histogram -> exclusive scan -> scatter (rp becomes END pointers)
__global__ void hist_rows(const int* __restrict__ rows, int* __restrict__ cnt) {
    int e = blockIdx.x * 256 + threadIdx.x;
    if (e < NE) atomicAdd(&cnt[rows[e]], 1);
}

__global__ void scan_block(int* __restrict__ data, int* __restrict__ sums) {
    __shared__ int s[SCAN_B];
    int i = blockIdx.x * SCAN_B + threadIdx.x;
    int v = (i < NN) ? data[i] : 0;
    s[threadIdx.x] = v;
    __syncthreads();
    for (int off = 1; off < SCAN_B; off <<= 1) {
        int t = (threadIdx.x >= off) ? s[threadIdx.x - off] : 0;
        __syncthreads();
        s[threadIdx.x] += t;
        __syncthreads();
    }
    if (i < NN) data[i] = s[threadIdx.x] - v;          // exclusive within chunk
    if (threadIdx.x == SCAN_B - 1) sums[blockIdx.x] = s[threadIdx.x];
}

__global__ void scan_sums(int* __restrict__ sums) {     // exclusive scan of NB block totals
    __shared__ int s[512];
    int v = (threadIdx.x < NB) ? sums[threadIdx.x] : 0;
    s[threadIdx.x] = v;
    __syncthreads();
    for (int off = 1; off < 512; off <<= 1) {
        int t = (threadIdx.x >= off) ? s[threadIdx.x - off] : 0;
        __syncthreads();
        s[threadIdx.x] += t;
        __syncthreads();
    }
    if (threadIdx.x < NB) sums[threadIdx.x] = s[threadIdx.x] - v;
}

__global__ void scan_add(int* __restrict__ data, const int* __restrict__ sums) {
    int i = blockIdx.x * SCAN_B + threadIdx.x;
    if (i < NN) data[i] += sums[blockIdx.x];
}

__global__ void scatter_edges(const int* __restrict__ rows, const int* __restrict__ cols,
                              const float* __restrict__ vals, int* __restrict__ rp,
                              int2* __restrict__ es) {
    int e = blockIdx.x * 256 + threadIdx.x;
    if (e >= NE) return;
    int pos = atomicAdd(&rp[rows[e]], 1);   // rp[r] ends as end-pointer == start of r+1
    es[pos] = make_int2(cols[e], __float_as_int(vals[e]));
}

// ---------------------------------------------------------------------------
// Fused layer 1 (F=3 aggregate): h = relu((0.9*A@x + 0.1*x0@Wi0)@Wx0); g = h@(0.9*Wx_mid0)
__global__ void layer1_fused(const int* __restrict__ rp, const int2* __restrict__ es,
                             const float* __restrict__ x0, const float* __restrict__ w_init0,
                             const float* __restrict__ w_x0, const float* __restrict__ w_x1,
                             float* __restrict__ g_out) {
    int tid = blockIdx.x * 256 + threadIdx.x;
    int n = tid >> 5, f = tid & 31;
    if (n >= NN) return;
    int s = (n == 0) ? 0 : rp[n - 1];
    int e_end = rp[n];
    float a0 = 0.f, a1 = 0.f, a2 = 0.f;
    for (int e = s + f; e < e_end; e += 32) {
        int2 ev = es[e];
        int c = ev.x; float v = __int_as_float(ev.y);
        a0 += v * x0[c * 3 + 0];
        a1 += v * x0[c * 3 + 1];
        a2 += v * x0[c * 3 + 2];
    }
    #pragma unroll
    for (int m = 16; m >= 1; m >>= 1) {
        a0 += __shfl_xor(a0, m, 32);
        a1 += __shfl_xor(a1, m, 32);
        a2 += __shfl_xor(a2, m, 32);
    }
    float p0 = x0[n * 3 + 0], p1 = x0[n * 3 + 1], p2 = x0[n * 3 + 2];
    float b0 = ALPHA * a0 + OMA * (p0 * w_init0[0] + p1 * w_init0[3] + p2 * w_init0[6]);
    float b1 = ALPHA * a1 + OMA * (p0 * w_init0[1] + p1 * w_init0[4] + p2 * w_init0[7]);
    float b2 = ALPHA * a2 + OMA * (p0 * w_init0[2] + p1 * w_init0[5] + p2 * w_init0[8]);
    float h = fmaxf(b0 * w_x0[f] + b1 * w_x0[HD + f] + b2 * w_x0[2 * HD + f], 0.f);
    float o = 0.f;
    #pragma unroll
    for (int k = 0; k < HD; ++k) o += __shfl(h, k, 32) * w_x1[k * HD + f];
    g_out[(size_t)n * HD + f] = ALPHA * o;
}

// Fused mid layer: h = relu(seed + A@g_in); MODE 0: g_out[N,32] = h@(0.9*Wx_next)
//                                           MODE 1: g_out[N]    = 0.9 * h . w_x_last
template<int MODE>
__global__ void mid_fused(const int* __restrict__ rp, const int2* __restrict__ es,
                          const float* __restrict__ g_in, const float* __restrict__ x0,
                          const float* __restrict__ wc, const float* __restrict__ w_next,
                          float* __restrict__ g_out) {
    int tid = blockIdx.x * 256 + threadIdx.x;
    int n = tid >> 5, f = tid & 31;
    if (n >= NN) return;
    int s = (n == 0) ? 0 : rp[n - 1];
    int e_end = rp[n];
    float acc = 0.f;
    for (int base = s; base < e_end; base += 32) {
        int e = base + f;
        int c = 0; float v = 0.f;
        if (e < e_end) { int2 ev = es[e]; c = ev.x; v = __int_as_float(ev.y); }
        int cnt = min(32, e_end - base);
        for (int k = 0; k < cnt; ++k) {
            int   ck = __shfl(c, k, 32);
            float vk = __shfl(v, k, 32);
            acc += vk * g_in[(size_t)ck * HD + f];
        }
    }
    float sd = x0[n * 3 + 0] * wc[f] + x0[n * 3 + 1] * wc[HD + f] + x0[n * 3 + 2] * wc[2 * HD + f];
    float h = fmaxf(sd + acc, 0.f);
    if (MODE == 0) {
        float o = 0.f;
        #pragma unroll
        for (int k = 0; k < HD; ++k) o += __shfl(h, k, 32) * w_next[k * HD + f];
        g_out[(size_t)n * HD + f] = ALPHA * o;
    } else {
        float t = h * w_next[f];
        #pragma unroll
        for (int m = 16; m >= 1; m >>= 1) t += __shfl_xor(t, m, 32);
        if (f == 0) g_out[n] = ALPHA * t;
    }
}

// Fused last layer (F=1): out = sigmoid(0.1*x0@WiL@WxL + A@g1)
__global__ void last_fused(const int* __restrict__ rp, const int2* __restrict__ es,
                           const float* __restrict__ g1, const float* __restrict__ x0,
                           const float* __restrict__ wcL, float* __restrict__ out) {
    int tid = blockIdx.x * 256 + threadIdx.x;
    int n = tid >> 5, f = tid & 31;
    if (n >= NN) return;
    int s = (n == 0) ? 0 : rp[n - 1];
    int e_end = rp[n];
    float acc = 0.f;
    for (int e = s + f; e < e_end; e += 32) {
        int2 ev = es[e];
        acc += __int_as_float(ev.y) * g1[ev.x];
    }
    #pragma unroll
    for (int m = 16; m >= 1; m >>= 1) acc += __shfl_xor(acc, m, 32);
    if (f == 0) {
        float z = x0[n * 3 + 0] * wcL[0] + x0[n * 3 + 1] * wcL[1] + x0[n * 3 + 2] * wcL[2] + acc;
        out[n] = 1.f / (1.f + __expf(-z));
    }
}

// ---------------------------------------------------------------------------
// Fallback path (round-1 atomic version) for small ws_size
__global__ void fb_spmm_f3(const int* __restrict__ rows, const int* __restrict__ cols,
                           const float* __restrict__ vals, const float* __restrict__ x,
                           float* __restrict__ agg3) {
    int e = blockIdx.x * blockDim.x + threadIdx.x;
    if (e >= NE) return;
    int r = rows[e], c = cols[e];
    float v = vals[e];
    atomicAdd(&agg3[r * 3 + 0], v * x[c * 3 + 0]);
    atomicAdd(&agg3[r * 3 + 1], v * x[c * 3 + 1]);
    atomicAdd(&agg3[r * 3 + 2], v * x[c * 3 + 2]);
}
__global__ void fb_epilogue1(const float* __restrict__ agg3, const float* __restrict__ x0,
                             const float* __restrict__ w_init0, const float* __restrict__ w_x0,
                             const float* __restrict__ w_x_next, float* __restrict__ g_out) {
    int tid = blockIdx.x * blockDim.x + threadIdx.x;
    int n = tid >> 5, f = tid & 31;
    if (n >= NN) return;
    float a0 = agg3[n * 3 + 0], a1 = agg3[n * 3 + 1], a2 = agg3[n * 3 + 2];
    float p0 = x0[n * 3 + 0], p1 = x0[n * 3 + 1], p2 = x0[n * 3 + 2];
    float b0 = ALPHA * a0 + OMA * (p0 * w_init0[0] + p1 * w_init0[3] + p2 * w_init0[6]);
    float b1 = ALPHA * a1 + OMA * (p0 * w_init0[1] + p1 * w_init0[4] + p2 * w_init0[7]);
    float b2 = ALPHA * a2 + OMA * (p0 * w_init0[2] + p1 * w_init0[5] + p2 * w_init0[8]);
    float h = fmaxf(b0 * w_x0[f] + b1 * w_x0[HD + f] + b2 * w_x0[2 * HD + f], 0.f);
    float acc = 0.f;
    #pragma unroll
    for (int k = 0; k < HD; ++k) acc += __shfl(h, k, 32) * w_x_next[k * HD + f];
    g_out[n * HD + f] = ALPHA * acc;
}
__global__ void fb_seed_mid(const float* __restrict__ x0, const float* __restrict__ wc,
                            float* __restrict__ agg) {
    int tid = blockIdx.x * blockDim.x + threadIdx.x;
    int n = tid >> 5, f = tid & 31;
    if (n >= NN) return;
    agg[n * HD + f] = x0[n * 3 + 0] * wc[f] + x0[n * 3 + 1] * wc[HD + f] + x0[n * 3 + 2] * wc[2 * HD + f];
}
__global__ void fb_spmm_f32(const int* __restrict__ rows, const int* __restrict__ cols,
                            const float* __restrict__ vals, const float* __restrict__ g,
                            float* __restrict__ agg) {
    int tid = blockIdx.x * blockDim.x + threadIdx.x;
    int e = tid >> 5, f = tid & 31;
    if (e >= NE) return;
    atomicAdd(&agg[rows[e] * HD + f], vals[e] * g[cols[e] * HD + f]);
}
__global__ void fb_epilogue_mid(const float* __restrict__ agg, const float* __restrict__ w_x_next,
                                float* __restrict__ g_out) {
    int tid = blockIdx.x * blockDim.x + threadIdx.x;
    int n = tid >> 5, f = tid & 31;
    if (n >= NN) return;
    float h = fmaxf(agg[n * HD + f], 0.f);
    float acc = 0.f;
    #pragma unroll
    for (int k = 0; k < HD; ++k) acc += __shfl(h, k, 32) * w_x_next[k * HD + f];
    g_out[n * HD + f] = ALPHA * acc;
}
__global__ void fb_epilogue_to1(const float* __restrict__ agg, const float* __restrict__ w_x_last,
                                float* __restrict__ g1) {
    int tid = blockIdx.x * blockDim.x + threadIdx.x;
    int n = tid >> 5, f = tid & 31;
    if (n >= NN) return;
    float v = fmaxf(agg[n * HD + f], 0.f) * w_x_last[f];
    #pragma unroll
    for (int m = 16; m >= 1; m >>= 1) v += __shfl_xor(v, m, 32);
    if (f == 0) g1[n] = ALPHA * v;
}
__global__ void fb_seed_last(const float* __restrict__ x0, const float* __restrict__ wcL,
                             float* __restrict__ aggL) {
    int n = blockIdx.x * blockDim.x + threadIdx.x;
    if (n >= NN) return;
    aggL[n] = x0[n * 3 + 0] * wcL[0] + x0[n * 3 + 1] * wcL[1] + x0[n * 3 + 2] * wcL[2];
}
__global__ void fb_spmm_f1(const int* __restrict__ rows, const int* __restrict__ cols,
                           const float* __restrict__ vals, const float* __restrict__ g1,
                           float* __restrict__ aggL) {
    int e = blockIdx.x * blockDim.x + threadIdx.x;
    if (e >= NE) return;
    atomicAdd(&aggL[rows[e]], vals[e] * g1[cols[e]]);
}
__global__ void fb_final_sigmoid(const float* __restrict__ aggL, float* __restrict__ out) {
    int n = blockIdx.x * blockDim.x + threadIdx.x;
    if (n >= NN) return;
    out[n] = 1.f / (1.f + __expf(-aggL[n]));
}

// ---------------------------------------------------------------------------
extern "C" void kernel_launch(void* const* d_in, const int* in_sizes, int n_in,
                              void* d_out, int out_size, void* d_ws, size_t ws_size,
                              hipStream_t stream) {
    const float* x           = (const float*)d_in[0];
    const int*   rows        = (const int*)d_in[1];
    const int*   cols        = (const int*)d_in[2];
    const float* vals        = (const float*)d_in[3];
    const float* w_init0     = (const float*)d_in[4];
    const float* w_x0        = (const float*)d_in[5];
    const float* w_init_mid  = (const float*)d_in[6];
    const float* w_x_mid     = (const float*)d_in[7];
    const float* w_init_last = (const float*)d_in[8];
    const float* w_x_last    = (const float*)d_in[9];
    float* out = (float*)d_out;

    const int B = 256;
    const int gridE   = NE / B;              // 62500 (exact)
    const int gridN32 = (NN * 32 + B - 1) / B;
    const int gridN   = (NN + B - 1) / B;

    const size_t SZ_ES = (size_t)NE * 8;     // 128 MB packed edges
    const size_t SZ_G  = (size_t)NN * HD * 4;// 64 MB
    const size_t SZ_RP = (size_t)NN * 4;     // 2 MB
    const size_t NEED  = SZ_ES + 2 * SZ_G + SZ_RP + 4096 + 4096;

    if (ws_size >= NEED) {
        char* p = (char*)d_ws;
        int2*  es     = (int2*)p;   p += SZ_ES;
        float* gA     = (float*)p;  p += SZ_G;
        float* gB     = (float*)p;  p += SZ_G;
        int*   rp     = (int*)p;    p += SZ_RP;
        int*   sums   = (int*)p;    p += 4096;
        float* wc_mid = (float*)p;
        float* wc_last = wc_mid + NMID * F0 * HD;
        float* g1 = gA;  // gA free by the time g1 is produced (ping-pong ends on gB)

        prep_weights<<<1, 1024, 0, stream>>>(w_init_mid, w_x_mid, w_init_last, w_x_last,
                                             wc_mid, wc_last);
        hipMemsetAsync(rp, 0, SZ_RP, stream);
        hist_rows<<<gridE, B, 0, stream>>>(rows, rp);
        scan_block<<<NB, SCAN_B, 0, stream>>>(rp, sums);
        scan_sums<<<1, 512, 0, stream>>>(sums);
        scan_add<<<NB, SCAN_B, 0, stream>>>(rp, sums);
        scatter_edges<<<gridE, B, 0, stream>>>(rows, cols, vals, rp, es);

        layer1_fused<<<gridN32, B, 0, stream>>>(rp, es, x, w_init0, w_x0, w_x_mid, gA);
        float* gin = gA; float* gout = gB;
        for (int i = 0; i < NMID - 1; ++i) {  // mid layers 0..4
            mid_fused<0><<<gridN32, B, 0, stream>>>(rp, es, gin, x, wc_mid + i * F0 * HD,
                                                    w_x_mid + (size_t)(i + 1) * HD * HD, gout);
            float* t = gin; gin = gout; gout = t;
        }
        // mid layer 5 -> g1 [N]   (gin == gB here)
        mid_fused<1><<<gridN32, B, 0, stream>>>(rp, es, gin, x, wc_mid + 5 * F0 * HD,
                                                w_x_last, g1);
        last_fused<<<gridN32, B, 0, stream>>>(rp, es, g1, x, wc_last, out);
    } else {
        // -------- fallback: round-1 atomic path (needs ~128 MB) --------
        char* ws = (char*)d_ws;
        float* g      = (float*)ws;
        float* agg    = (float*)(ws + SZ_G);
        float* wc_mid = (float*)(ws + 2 * SZ_G);
        float* wc_last = wc_mid + NMID * F0 * HD;

        prep_weights<<<1, 1024, 0, stream>>>(w_init_mid, w_x_mid, w_init_last, w_x_last,
                                             wc_mid, wc_last);
        hipMemsetAsync(agg, 0, (size_t)NN * 3 * sizeof(float), stream);
        fb_spmm_f3<<<gridE, B, 0, stream>>>(rows, cols, vals, x, agg);
        fb_epilogue1<<<gridN32, B, 0, stream>>>(agg, x, w_init0, w_x0, w_x_mid, g);
        const int gridE32 = (int)(((size_t)NE * 32) / B);
        for (int i = 0; i < NMID; ++i) {
            fb_seed_mid<<<gridN32, B, 0, stream>>>(x, wc_mid + i * F0 * HD, agg);
            fb_spmm_f32<<<gridE32, B, 0, stream>>>(rows, cols, vals, g, agg);
            if (i < NMID - 1)
                fb_epilogue_mid<<<gridN32, B, 0, stream>>>(agg, w_x_mid + (size_t)(i + 1) * HD * HD, g);
            else
                fb_epilogue_to1<<<gridN32, B, 0, stream>>>(agg, w_x_last, g);
        }
        fb_seed_last<<<gridN, B, 0, stream>>>(x, wc_last, agg);
        fb_spmm_f1<<<gridE, B, 0, stream>>>(rows, cols, vals, g, agg);
        fb_final_sigmoid<<<gridN, B, 0, stream>>>(agg, out);
    }
}

// Round 3
// 2966.096 us; speedup vs baseline: 4.6621x; 1.5604x over previous
//
#include <hip/hip_runtime.h>

#define NN 500000      // nodes
#define NE 16000000    // edges
#define HD 32          // hidden
#define NMID 6
#define F0 3

#define RPB 1024                         // rows per bucket (pow2)
#define NBUK ((NN + RPB - 1) / RPB)      // 489 buckets
#define GRID_P 2048                      // blocks for hist/scatter pass
#define EBLK ((NE + GRID_P - 1) / GRID_P)// 7813 edges per block

static constexpr float ALPHA = 0.9f;
static constexpr float OMA = 1.0f - 0.9f; // 0.1

// ---------------------------------------------------------------------------
// wc_mid[i] = 0.1 * (w_init_mid[i] @ w_x_mid[i])  [3,32];  wc_last = 0.1*(Wi_L @ Wx_L) [3]
__global__ void prep_weights(const float* __restrict__ w_init_mid,
                             const float* __restrict__ w_x_mid,
                             const float* __restrict__ w_init_last,
                             const float* __restrict__ w_x_last,
                             float* __restrict__ wc_mid,
                             float* __restrict__ wc_last) {
    int t = threadIdx.x;
    if (t < NMID * F0 * HD) {
        int i = t / (F0 * HD);
        int r = t - i * (F0 * HD);
        int k = r / HD, f = r % HD;
        const float* wi = w_init_mid + (size_t)i * F0 * HD;
        const float* wx = w_x_mid + (size_t)i * HD * HD;
        float acc = 0.f;
        for (int j = 0; j < HD; ++j) acc += wi[k * HD + j] * wx[j * HD + f];
        wc_mid[t] = OMA * acc;
    } else if (t < NMID * F0 * HD + F0) {
        int k = t - NMID * F0 * HD;
        float acc = 0.f;
        for (int j = 0; j < HD; ++j) acc += w_init_last[k * HD + j] * w_x_last[j];
        wc_last[k] = OMA * acc;
    }
}

// ---------------------------------------------------------------------------
// Build stage A: per-bucket edge counts (LDS histogram, 1 global atomic per
// block per non-empty bucket).
__global__ void bucket_hist(const int* __restrict__ rows, int* __restrict__ cnt) {
    __shared__ int lh[512];
    int tid = threadIdx.x;
    lh[tid] = 0;
    __syncthreads();
    int e0 = blockIdx.x * EBLK;
    int e1 = min(e0 + EBLK, NE);
    for (int e = e0 + tid; e < e1; e += 512)
        atomicAdd(&lh[rows[e] >> 10], 1);
    __syncthreads();
    if (tid < NBUK && lh[tid]) atomicAdd(&cnt[tid], lh[tid]);
}

// Build stage B: exclusive scan of bucket counts (in place). cnt -> bucket starts.
__global__ void scan_buckets(int* __restrict__ cnt) {
    __shared__ int s[512];
    int tid = threadIdx.x;
    int v = (tid < NBUK) ? cnt[tid] : 0;
    s[tid] = v;
    __syncthreads();
    for (int off = 1; off < 512; off <<= 1) {
        int t = (tid >= off) ? s[tid - off] : 0;
        __syncthreads();
        s[tid] += t;
        __syncthreads();
    }
    if (tid < NBUK) cnt[tid] = s[tid] - v;   // exclusive
}

// Build stage C: scatter edges into bucket-major tmp. Each block reserves a
// contiguous run per bucket (line-dense writes). tmp entry packs
// (rowlocal<<19)|col in .x, val bits in .y. After this, tail[b] = bucket end.
__global__ void p1_scatter(const int* __restrict__ rows, const int* __restrict__ cols,
                           const float* __restrict__ vals, int* __restrict__ tail,
                           int2* __restrict__ tmp) {
    __shared__ int lh[512], gb[512], lp[512];
    int tid = threadIdx.x;
    lh[tid] = 0;
    __syncthreads();
    int e0 = blockIdx.x * EBLK;
    int e1 = min(e0 + EBLK, NE);
    for (int e = e0 + tid; e < e1; e += 512)
        atomicAdd(&lh[rows[e] >> 10], 1);
    __syncthreads();
    if (tid < NBUK && lh[tid]) gb[tid] = atomicAdd(&tail[tid], lh[tid]);
    lp[tid] = 0;
    __syncthreads();
    for (int e = e0 + tid; e < e1; e += 512) {
        int r = rows[e];
        int b = r >> 10;
        int loc = atomicAdd(&lp[b], 1);
        int pos = gb[b] + loc;
        tmp[pos] = make_int2(((r & (RPB - 1)) << 19) | cols[e], __float_as_int(vals[e]));
    }
}

// Build stage D: one block per bucket. LDS row-hist + scan -> exact CSR
// (rp = end pointers), then scatter into the bucket's 256 KB es window.
__global__ void __launch_bounds__(1024) p2_csr(const int* __restrict__ tail,
                                               const int2* __restrict__ tmp,
                                               int* __restrict__ rp,
                                               int2* __restrict__ es) {
    __shared__ int a[RPB];     // counts -> inclusive scan
    __shared__ int tl[RPB];    // row write tails
    int b = blockIdx.x, tid = threadIdx.x;
    int estart = (b == 0) ? 0 : tail[b - 1];
    int eend = tail[b];
    a[tid] = 0;
    __syncthreads();
    for (int e = estart + tid; e < eend; e += RPB)
        atomicAdd(&a[tmp[e].x >> 19], 1);
    __syncthreads();
    int myc = a[tid];
    for (int off = 1; off < RPB; off <<= 1) {
        int t = (tid >= off) ? a[tid - off] : 0;
        __syncthreads();
        a[tid] += t;
        __syncthreads();
    }
    int rend = estart + a[tid];        // end offset of row (b*RPB + tid)
    tl[tid] = rend - myc;              // start offset
    int grow = b * RPB + tid;
    if (grow < NN) rp[grow] = rend;
    __syncthreads();
    for (int e = estart + tid; e < eend; e += RPB) {
        int2 t = tmp[e];
        int rl = t.x >> 19;
        int pos = atomicAdd(&tl[rl], 1);
        es[pos] = make_int2(t.x & 0x7FFFF, t.y);
    }
}

// ---------------------------------------------------------------------------
// Fused layer 1 (F=3 aggregate): h = relu((0.9*A@x + 0.1*x0@Wi0)@Wx0); g = h@(0.9*Wx_mid0)
__global__ void layer1_fused(const int* __restrict__ rp, const int2* __restrict__ es,
                             const float* __restrict__ x0, const float* __restrict__ w_init0,
                             const float* __restrict__ w_x0, const float* __restrict__ w_x1,
                             float* __restrict__ g_out) {
    int tid = blockIdx.x * 256 + threadIdx.x;
    int n = tid >> 5, f = tid & 31;
    if (n >= NN) return;
    int s = (n == 0) ? 0 : rp[n - 1];
    int e_end = rp[n];
    float a0 = 0.f, a1 = 0.f, a2 = 0.f;
    for (int e = s + f; e < e_end; e += 32) {
        int2 ev = es[e];
        int c = ev.x; float v = __int_as_float(ev.y);
        a0 += v * x0[c * 3 + 0];
        a1 += v * x0[c * 3 + 1];
        a2 += v * x0[c * 3 + 2];
    }
    #pragma unroll
    for (int m = 16; m >= 1; m >>= 1) {
        a0 += __shfl_xor(a0, m, 32);
        a1 += __shfl_xor(a1, m, 32);
        a2 += __shfl_xor(a2, m, 32);
    }
    float p0 = x0[n * 3 + 0], p1 = x0[n * 3 + 1], p2 = x0[n * 3 + 2];
    float b0 = ALPHA * a0 + OMA * (p0 * w_init0[0] + p1 * w_init0[3] + p2 * w_init0[6]);
    float b1 = ALPHA * a1 + OMA * (p0 * w_init0[1] + p1 * w_init0[4] + p2 * w_init0[7]);
    float b2 = ALPHA * a2 + OMA * (p0 * w_init0[2] + p1 * w_init0[5] + p2 * w_init0[8]);
    float h = fmaxf(b0 * w_x0[f] + b1 * w_x0[HD + f] + b2 * w_x0[2 * HD + f], 0.f);
    float o = 0.f;
    #pragma unroll
    for (int k = 0; k < HD; ++k) o += __shfl(h, k, 32) * w_x1[k * HD + f];
    g_out[(size_t)n * HD + f] = ALPHA * o;
}

// Fused mid layer: h = relu(seed + A@g_in). Inner gather loop pipelined 8-deep
// (pad chunks with v=0 so the unrolled path is branch-free).
// MODE 0: g_out[N,32] = h@(0.9*Wx_next);  MODE 1: g_out[N] = 0.9 * h . w_x_last
template<int MODE>
__global__ void mid_fused(const int* __restrict__ rp, const int2* __restrict__ es,
                          const float* __restrict__ g_in, const float* __restrict__ x0,
                          const float* __restrict__ wc, const float* __restrict__ w_next,
                          float* __restrict__ g_out) {
    int tid = blockIdx.x * 256 + threadIdx.x;
    int n = tid >> 5, f = tid & 31;
    if (n >= NN) return;
    int s = (n == 0) ? 0 : rp[n - 1];
    int e_end = rp[n];
    float acc = 0.f;
    for (int base = s; base < e_end; base += 32) {
        int e = base + f;
        int c = 0; float v = 0.f;
        if (e < e_end) { int2 ev = es[e]; c = ev.x; v = __int_as_float(ev.y); }
        #pragma unroll
        for (int k = 0; k < 32; k += 8) {
            int ck[8]; float vk[8], gk[8];
            #pragma unroll
            for (int j = 0; j < 8; ++j) { ck[j] = __shfl(c, k + j, 32); vk[j] = __shfl(v, k + j, 32); }
            #pragma unroll
            for (int j = 0; j < 8; ++j) gk[j] = g_in[((size_t)ck[j] << 5) + f];
            #pragma unroll
            for (int j = 0; j < 8; ++j) acc = fmaf(vk[j], gk[j], acc);
        }
    }
    float sd = x0[n * 3 + 0] * wc[f] + x0[n * 3 + 1] * wc[HD + f] + x0[n * 3 + 2] * wc[2 * HD + f];
    float h = fmaxf(sd + acc, 0.f);
    if (MODE == 0) {
        float o = 0.f;
        #pragma unroll
        for (int k = 0; k < HD; ++k) o += __shfl(h, k, 32) * w_next[k * HD + f];
        g_out[(size_t)n * HD + f] = ALPHA * o;
    } else {
        float t = h * w_next[f];
        #pragma unroll
        for (int m = 16; m >= 1; m >>= 1) t += __shfl_xor(t, m, 32);
        if (f == 0) g_out[n] = ALPHA * t;
    }
}

// Fused last layer (F=1): out = sigmoid(0.1*x0@WiL@WxL + A@g1)
__global__ void last_fused(const int* __restrict__ rp, const int2* __restrict__ es,
                           const float* __restrict__ g1, const float* __restrict__ x0,
                           const float* __restrict__ wcL, float* __restrict__ out) {
    int tid = blockIdx.x * 256 + threadIdx.x;
    int n = tid >> 5, f = tid & 31;
    if (n >= NN) return;
    int s = (n == 0) ? 0 : rp[n - 1];
    int e_end = rp[n];
    float acc = 0.f;
    for (int e = s + f; e < e_end; e += 32) {
        int2 ev = es[e];
        acc += __int_as_float(ev.y) * g1[ev.x];
    }
    #pragma unroll
    for (int m = 16; m >= 1; m >>= 1) acc += __shfl_xor(acc, m, 32);
    if (f == 0) {
        float z = x0[n * 3 + 0] * wcL[0] + x0[n * 3 + 1] * wcL[1] + x0[n * 3 + 2] * wcL[2] + acc;
        out[n] = 1.f / (1.f + __expf(-z));
    }
}

// ---------------------------------------------------------------------------
// Fallback path (atomic version) for small ws_size
__global__ void fb_spmm_f3(const int* __restrict__ rows, const int* __restrict__ cols,
                           const float* __restrict__ vals, const float* __restrict__ x,
                           float* __restrict__ agg3) {
    int e = blockIdx.x * blockDim.x + threadIdx.x;
    if (e >= NE) return;
    int r = rows[e], c = cols[e];
    float v = vals[e];
    atomicAdd(&agg3[r * 3 + 0], v * x[c * 3 + 0]);
    atomicAdd(&agg3[r * 3 + 1], v * x[c * 3 + 1]);
    atomicAdd(&agg3[r * 3 + 2], v * x[c * 3 + 2]);
}
__global__ void fb_epilogue1(const float* __restrict__ agg3, const float* __restrict__ x0,
                             const float* __restrict__ w_init0, const float* __restrict__ w_x0,
                             const float* __restrict__ w_x_next, float* __restrict__ g_out) {
    int tid = blockIdx.x * blockDim.x + threadIdx.x;
    int n = tid >> 5, f = tid & 31;
    if (n >= NN) return;
    float a0 = agg3[n * 3 + 0], a1 = agg3[n * 3 + 1], a2 = agg3[n * 3 + 2];
    float p0 = x0[n * 3 + 0], p1 = x0[n * 3 + 1], p2 = x0[n * 3 + 2];
    float b0 = ALPHA * a0 + OMA * (p0 * w_init0[0] + p1 * w_init0[3] + p2 * w_init0[6]);
    float b1 = ALPHA * a1 + OMA * (p0 * w_init0[1] + p1 * w_init0[4] + p2 * w_init0[7]);
    float b2 = ALPHA * a2 + OMA * (p0 * w_init0[2] + p1 * w_init0[5] + p2 * w_init0[8]);
    float h = fmaxf(b0 * w_x0[f] + b1 * w_x0[HD + f] + b2 * w_x0[2 * HD + f], 0.f);
    float acc = 0.f;
    #pragma unroll
    for (int k = 0; k < HD; ++k) acc += __shfl(h, k, 32) * w_x_next[k * HD + f];
    g_out[n * HD + f] = ALPHA * acc;
}
__global__ void fb_seed_mid(const float* __restrict__ x0, const float* __restrict__ wc,
                            float* __restrict__ agg) {
    int tid = blockIdx.x * blockDim.x + threadIdx.x;
    int n = tid >> 5, f = tid & 31;
    if (n >= NN) return;
    agg[n * HD + f] = x0[n * 3 + 0] * wc[f] + x0[n * 3 + 1] * wc[HD + f] + x0[n * 3 + 2] * wc[2 * HD + f];
}
__global__ void fb_spmm_f32(const int* __restrict__ rows, const int* __restrict__ cols,
                            const float* __restrict__ vals, const float* __restrict__ g,
                            float* __restrict__ agg) {
    int tid = blockIdx.x * blockDim.x + threadIdx.x;
    int e = tid >> 5, f = tid & 31;
    if (e >= NE) return;
    atomicAdd(&agg[rows[e] * HD + f], vals[e] * g[cols[e] * HD + f]);
}
__global__ void fb_epilogue_mid(const float* __restrict__ agg, const float* __restrict__ w_x_next,
                                float* __restrict__ g_out) {
    int tid = blockIdx.x * blockDim.x + threadIdx.x;
    int n = tid >> 5, f = tid & 31;
    if (n >= NN) return;
    float h = fmaxf(agg[n * HD + f], 0.f);
    float acc = 0.f;
    #pragma unroll
    for (int k = 0; k < HD; ++k) acc += __shfl(h, k, 32) * w_x_next[k * HD + f];
    g_out[n * HD + f] = ALPHA * acc;
}
__global__ void fb_epilogue_to1(const float* __restrict__ agg, const float* __restrict__ w_x_last,
                                float* __restrict__ g1) {
    int tid = blockIdx.x * blockDim.x + threadIdx.x;
    int n = tid >> 5, f = tid & 31;
    if (n >= NN) return;
    float v = fmaxf(agg[n * HD + f], 0.f) * w_x_last[f];
    #pragma unroll
    for (int m = 16; m >= 1; m >>= 1) v += __shfl_xor(v, m, 32);
    if (f == 0) g1[n] = ALPHA * v;
}
__global__ void fb_seed_last(const float* __restrict__ x0, const float* __restrict__ wcL,
                             float* __restrict__ aggL) {
    int n = blockIdx.x * blockDim.x + threadIdx.x;
    if (n >= NN) return;
    aggL[n] = x0[n * 3 + 0] * wcL[0] + x0[n * 3 + 1] * wcL[1] + x0[n * 3 + 2] * wcL[2];
}
__global__ void fb_spmm_f1(const int* __restrict__ rows, const int* __restrict__ cols,
                           const float* __restrict__ vals, const float* __restrict__ g1,
                           float* __restrict__ aggL) {
    int e = blockIdx.x * blockDim.x + threadIdx.x;
    if (e >= NE) return;
    atomicAdd(&aggL[rows[e]], vals[e] * g1[cols[e]]);
}
__global__ void fb_final_sigmoid(const float* __restrict__ aggL, float* __restrict__ out) {
    int n = blockIdx.x * blockDim.x + threadIdx.x;
    if (n >= NN) return;
    out[n] = 1.f / (1.f + __expf(-aggL[n]));
}

// ---------------------------------------------------------------------------
extern "C" void kernel_launch(void* const* d_in, const int* in_sizes, int n_in,
                              void* d_out, int out_size, void* d_ws, size_t ws_size,
                              hipStream_t stream) {
    const float* x           = (const float*)d_in[0];
    const int*   rows        = (const int*)d_in[1];
    const int*   cols        = (const int*)d_in[2];
    const float* vals        = (const float*)d_in[3];
    const float* w_init0     = (const float*)d_in[4];
    const float* w_x0        = (const float*)d_in[5];
    const float* w_init_mid  = (const float*)d_in[6];
    const float* w_x_mid     = (const float*)d_in[7];
    const float* w_init_last = (const float*)d_in[8];
    const float* w_x_last    = (const float*)d_in[9];
    float* out = (float*)d_out;

    const int B = 256;
    const int gridE   = NE / B;
    const int gridN32 = (NN * 32 + B - 1) / B;
    const int gridN   = (NN + B - 1) / B;

    const size_t SZ_ES = (size_t)NE * 8;      // 128 MB packed edges
    const size_t SZ_G  = (size_t)NN * HD * 4; // 64 MB
    const size_t SZ_RP = (size_t)NN * 4;      // 2 MB
    const size_t NEED  = SZ_ES + 2 * SZ_G + SZ_RP + 4096 + 4096; // same as round 2

    if (ws_size >= NEED) {
        char* p = (char*)d_ws;
        int2*  es     = (int2*)p;   p += SZ_ES;
        float* gA     = (float*)p;              // aliases tmp (tmp dead before gA live)
        float* gB     = (float*)(p + SZ_G);
        int2*  tmp    = (int2*)p;   p += 2 * SZ_G;
        int*   rp     = (int*)p;    p += SZ_RP;
        int*   bkt    = (int*)p;    p += 4096;  // NBUK counters / starts / ends
        float* wc_mid = (float*)p;
        float* wc_last = wc_mid + NMID * F0 * HD;
        float* g1 = gA;

        prep_weights<<<1, 1024, 0, stream>>>(w_init_mid, w_x_mid, w_init_last, w_x_last,
                                             wc_mid, wc_last);
        hipMemsetAsync(bkt, 0, NBUK * sizeof(int), stream);
        bucket_hist<<<GRID_P, 512, 0, stream>>>(rows, bkt);
        scan_buckets<<<1, 512, 0, stream>>>(bkt);
        p1_scatter<<<GRID_P, 512, 0, stream>>>(rows, cols, vals, bkt, tmp);
        p2_csr<<<NBUK, RPB, 0, stream>>>(bkt, tmp, rp, es);

        layer1_fused<<<gridN32, B, 0, stream>>>(rp, es, x, w_init0, w_x0, w_x_mid, gA);
        float* gin = gA; float* gout = gB;
        for (int i = 0; i < NMID - 1; ++i) {
            mid_fused<0><<<gridN32, B, 0, stream>>>(rp, es, gin, x, wc_mid + i * F0 * HD,
                                                    w_x_mid + (size_t)(i + 1) * HD * HD, gout);
            float* t = gin; gin = gout; gout = t;
        }
        mid_fused<1><<<gridN32, B, 0, stream>>>(rp, es, gin, x, wc_mid + 5 * F0 * HD,
                                                w_x_last, g1);
        last_fused<<<gridN32, B, 0, stream>>>(rp, es, g1, x, wc_last, out);
    } else {
        // -------- fallback: atomic path --------
        char* ws = (char*)d_ws;
        float* g      = (float*)ws;
        float* agg    = (float*)(ws + SZ_G);
        float* wc_mid = (float*)(ws + 2 * SZ_G);
        float* wc_last = wc_mid + NMID * F0 * HD;

        prep_weights<<<1, 1024, 0, stream>>>(w_init_mid, w_x_mid, w_init_last, w_x_last,
                                             wc_mid, wc_last);
        hipMemsetAsync(agg, 0, (size_t)NN * 3 * sizeof(float), stream);
        fb_spmm_f3<<<gridE, B, 0, stream>>>(rows, cols, vals, x, agg);
        fb_epilogue1<<<gridN32, B, 0, stream>>>(agg, x, w_init0, w_x0, w_x_mid, g);
        const int gridE32 = (int)(((size_t)NE * 32) / B);
        for (int i = 0; i < NMID; ++i) {
            fb_seed_mid<<<gridN32, B, 0, stream>>>(x, wc_mid + i * F0 * HD, agg);
            fb_spmm_f32<<<gridE32, B, 0, stream>>>(rows, cols, vals, g, agg);
            if (i < NMID - 1)
                fb_epilogue_mid<<<gridN32, B, 0, stream>>>(agg, w_x_mid + (size_t)(i + 1) * HD * HD, g);
            else
                fb_epilogue_to1<<<gridN32, B, 0, stream>>>(agg, w_x_last, g);
        }
        fb_seed_last<<<gridN, B, 0, stream>>>(x, wc_last, agg);
        fb_spmm_f1<<<gridE, B, 0, stream>>>(rows, cols, vals, g, agg);
        fb_final_sigmoid<<<gridN, B, 0, stream>>>(agg, out);
    }
}

// Round 4
// 2469.188 us; speedup vs baseline: 5.6003x; 1.2012x over previous
//
#include <hip/hip_runtime.h>
#include <hip/hip_fp16.h>

#define NN 500000      // nodes
#define NE 16000000    // edges
#define HD 32          // hidden
#define NMID 6
#define F0 3

#define RPB 1024                         // rows per bucket (pow2)
#define NBUK ((NN + RPB - 1) / RPB)      // 489 buckets
#define GRID_P 2048                      // blocks for hist/scatter pass
#define EBLK ((NE + GRID_P - 1) / GRID_P)// edges per block

static constexpr float ALPHA = 0.9f;
static constexpr float OMA = 1.0f - 0.9f; // 0.1

// ---------------------------------------------------------------------------
// Packed weight prep (runs AFTER the CSR build; weights live in dead tmp space):
//  wpk[i][k][f] (i=0..4, k,f in [0,16)) = {Wx_mid[i+1][2k][2f], [2k][2f+1], [2k+1][2f], [2k+1][2f+1]}
//  wc2[i][k3][f] = 0.1 * { (Wi_mid[i] @ Wx_mid[i])[k3][2f], [k3][2f+1] }
//  wcl[k3] = 0.1 * (Wi_last @ Wx_last)[k3]
__global__ void prep_pack(const float* __restrict__ w_init_mid,
                          const float* __restrict__ w_x_mid,
                          const float* __restrict__ w_init_last,
                          const float* __restrict__ w_x_last,
                          float4* __restrict__ wpk,
                          float2* __restrict__ wc2,
                          float* __restrict__ wcl) {
    int t = blockIdx.x * 512 + threadIdx.x;
    if (t < 5 * 256) {
        int i = t >> 8, r = t & 255, k = r >> 4, f = r & 15;
        const float* W = w_x_mid + (size_t)(i + 1) * HD * HD;
        wpk[t] = make_float4(W[(2 * k) * HD + 2 * f], W[(2 * k) * HD + 2 * f + 1],
                             W[(2 * k + 1) * HD + 2 * f], W[(2 * k + 1) * HD + 2 * f + 1]);
    } else if (t < 5 * 256 + NMID * 48) {
        int r = t - 1280;
        int i = r / 48, rr = r % 48, k = rr >> 4, f = rr & 15;
        const float* wi = w_init_mid + (size_t)i * F0 * HD;
        const float* wx = w_x_mid + (size_t)i * HD * HD;
        float a = 0.f, b = 0.f;
        for (int j = 0; j < HD; ++j) {
            a += wi[k * HD + j] * wx[j * HD + 2 * f];
            b += wi[k * HD + j] * wx[j * HD + 2 * f + 1];
        }
        wc2[r] = make_float2(OMA * a, OMA * b);
    } else if (t < 1280 + NMID * 48 + F0) {
        int k = t - (1280 + NMID * 48);
        float a = 0.f;
        for (int j = 0; j < HD; ++j) a += w_init_last[k * HD + j] * w_x_last[j];
        wcl[k] = OMA * a;
    }
}

// ---------------------------------------------------------------------------
// CSR build (unchanged from round 3)
__global__ void bucket_hist(const int* __restrict__ rows, int* __restrict__ cnt) {
    __shared__ int lh[512];
    int tid = threadIdx.x;
    lh[tid] = 0;
    __syncthreads();
    int e0 = blockIdx.x * EBLK;
    int e1 = min(e0 + EBLK, NE);
    for (int e = e0 + tid; e < e1; e += 512)
        atomicAdd(&lh[rows[e] >> 10], 1);
    __syncthreads();
    if (tid < NBUK && lh[tid]) atomicAdd(&cnt[tid], lh[tid]);
}

__global__ void scan_buckets(int* __restrict__ cnt) {
    __shared__ int s[512];
    int tid = threadIdx.x;
    int v = (tid < NBUK) ? cnt[tid] : 0;
    s[tid] = v;
    __syncthreads();
    for (int off = 1; off < 512; off <<= 1) {
        int t = (tid >= off) ? s[tid - off] : 0;
        __syncthreads();
        s[tid] += t;
        __syncthreads();
    }
    if (tid < NBUK) cnt[tid] = s[tid] - v;
}

__global__ void p1_scatter(const int* __restrict__ rows, const int* __restrict__ cols,
                           const float* __restrict__ vals, int* __restrict__ tail,
                           int2* __restrict__ tmp) {
    __shared__ int lh[512], gb[512], lp[512];
    int tid = threadIdx.x;
    lh[tid] = 0;
    __syncthreads();
    int e0 = blockIdx.x * EBLK;
    int e1 = min(e0 + EBLK, NE);
    for (int e = e0 + tid; e < e1; e += 512)
        atomicAdd(&lh[rows[e] >> 10], 1);
    __syncthreads();
    if (tid < NBUK && lh[tid]) gb[tid] = atomicAdd(&tail[tid], lh[tid]);
    lp[tid] = 0;
    __syncthreads();
    for (int e = e0 + tid; e < e1; e += 512) {
        int r = rows[e];
        int b = r >> 10;
        int loc = atomicAdd(&lp[b], 1);
        int pos = gb[b] + loc;
        tmp[pos] = make_int2(((r & (RPB - 1)) << 19) | cols[e], __float_as_int(vals[e]));
    }
}

__global__ void __launch_bounds__(1024) p2_csr(const int* __restrict__ tail,
                                               const int2* __restrict__ tmp,
                                               int* __restrict__ rp,
                                               int2* __restrict__ es) {
    __shared__ int a[RPB];
    __shared__ int tl[RPB];
    int b = blockIdx.x, tid = threadIdx.x;
    int estart = (b == 0) ? 0 : tail[b - 1];
    int eend = tail[b];
    a[tid] = 0;
    __syncthreads();
    for (int e = estart + tid; e < eend; e += RPB)
        atomicAdd(&a[tmp[e].x >> 19], 1);
    __syncthreads();
    int myc = a[tid];
    for (int off = 1; off < RPB; off <<= 1) {
        int t = (tid >= off) ? a[tid - off] : 0;
        __syncthreads();
        a[tid] += t;
        __syncthreads();
    }
    int rend = estart + a[tid];
    tl[tid] = rend - myc;
    int grow = b * RPB + tid;
    if (grow < NN) rp[grow] = rend;
    __syncthreads();
    for (int e = estart + tid; e < eend; e += RPB) {
        int2 t = tmp[e];
        int rl = t.x >> 19;
        int pos = atomicAdd(&tl[rl], 1);
        es[pos] = make_int2(t.x & 0x7FFFF, t.y);
    }
}

// ---------------------------------------------------------------------------
// Fused layer 1 (F=3 aggregate), 32 lanes/node; OUTPUT packed fp16 pairs.
__global__ void layer1_fused(const int* __restrict__ rp, const int2* __restrict__ es,
                             const float* __restrict__ x0, const float* __restrict__ w_init0,
                             const float* __restrict__ w_x0, const float* __restrict__ w_x1,
                             unsigned int* __restrict__ gh_out) {
    int tid = blockIdx.x * 256 + threadIdx.x;
    int n = tid >> 5, f = tid & 31;
    if (n >= NN) return;
    int s = (n == 0) ? 0 : rp[n - 1];
    int e_end = rp[n];
    float a0 = 0.f, a1 = 0.f, a2 = 0.f;
    for (int e = s + f; e < e_end; e += 32) {
        int2 ev = es[e];
        int c = ev.x; float v = __int_as_float(ev.y);
        a0 += v * x0[c * 3 + 0];
        a1 += v * x0[c * 3 + 1];
        a2 += v * x0[c * 3 + 2];
    }
    #pragma unroll
    for (int m = 16; m >= 1; m >>= 1) {
        a0 += __shfl_xor(a0, m, 32);
        a1 += __shfl_xor(a1, m, 32);
        a2 += __shfl_xor(a2, m, 32);
    }
    float p0 = x0[n * 3 + 0], p1 = x0[n * 3 + 1], p2 = x0[n * 3 + 2];
    float b0 = ALPHA * a0 + OMA * (p0 * w_init0[0] + p1 * w_init0[3] + p2 * w_init0[6]);
    float b1 = ALPHA * a1 + OMA * (p0 * w_init0[1] + p1 * w_init0[4] + p2 * w_init0[7]);
    float b2 = ALPHA * a2 + OMA * (p0 * w_init0[2] + p1 * w_init0[5] + p2 * w_init0[8]);
    float h = fmaxf(b0 * w_x0[f] + b1 * w_x0[HD + f] + b2 * w_x0[2 * HD + f], 0.f);
    float o = 0.f;
    #pragma unroll
    for (int k = 0; k < HD; ++k) o += __shfl(h, k, 32) * w_x1[k * HD + f];
    o *= ALPHA;
    float o_hi = __shfl_down(o, 1, 32);
    if ((f & 1) == 0) {
        __half2 hp;
        hp.x = __float2half_rn(o);
        hp.y = __float2half_rn(o_hi);
        gh_out[(size_t)n * 16 + (f >> 1)] = *(unsigned int*)&hp;
    }
}

// ---------------------------------------------------------------------------
// Fused mid layer, 16 lanes/node, fp16 packed feature pairs.
// Per 16-edge chunk: coalesced es load -> LDS stage -> 16 uniform ds_read_b64
// broadcasts -> 16 gathers (64 B line each) in flight -> f32 accumulate.
// MODE 0: gh_out[n][f] = pack2(0.9 * h @ Wx_next)   (wpk packed float4)
// MODE 1: g1_out[n]    = 0.9 * h . w_x_last
template<int MODE>
__global__ void mid_fused(const int* __restrict__ rp, const int2* __restrict__ es,
                          const unsigned int* __restrict__ gh_in,
                          const float* __restrict__ x0,
                          const float2* __restrict__ wc2,
                          const float4* __restrict__ wpk,
                          const float* __restrict__ w_last,
                          float* __restrict__ g1_out,
                          unsigned int* __restrict__ gh_out) {
    int tid = blockIdx.x * 256 + threadIdx.x;
    int n = tid >> 4, f = tid & 15;
    if (n >= NN) return;
    int grp = threadIdx.x >> 4;          // 16 groups per block
    __shared__ int2 stage[16][16];
    int s = (n == 0) ? 0 : rp[n - 1];
    int e_end = rp[n];
    float acc0 = 0.f, acc1 = 0.f;
    for (int base = s; base < e_end; base += 16) {
        int e = base + f;
        int2 ev = (e < e_end) ? es[e] : make_int2(0, 0);
        stage[grp][f] = ev;              // wave-synchronous within 16-lane group
        int2 ee[16];
        #pragma unroll
        for (int k = 0; k < 16; ++k) ee[k] = stage[grp][k];   // uniform broadcast reads
        unsigned int gw[16];
        #pragma unroll
        for (int k = 0; k < 16; ++k) gw[k] = gh_in[(ee[k].x << 4) + f];
        #pragma unroll
        for (int k = 0; k < 16; ++k) {
            float v = __int_as_float(ee[k].y);
            __half2 h2 = *(__half2*)&gw[k];
            float2 gf = __half22float2(h2);
            acc0 = fmaf(v, gf.x, acc0);
            acc1 = fmaf(v, gf.y, acc1);
        }
    }
    float xa = x0[n * 3 + 0], xb = x0[n * 3 + 1], xc = x0[n * 3 + 2];
    float2 w0 = wc2[f], w1 = wc2[16 + f], w2 = wc2[32 + f];
    float h0 = fmaxf(xa * w0.x + xb * w1.x + xc * w2.x + acc0, 0.f);
    float h1 = fmaxf(xa * w0.y + xb * w1.y + xc * w2.y + acc1, 0.f);
    if (MODE == 0) {
        float o0 = 0.f, o1 = 0.f;
        #pragma unroll
        for (int k = 0; k < 16; ++k) {
            float ha = __shfl(h0, k, 16);
            float hb = __shfl(h1, k, 16);
            float4 w = wpk[k * 16 + f];
            o0 += ha * w.x + hb * w.z;
            o1 += ha * w.y + hb * w.w;
        }
        __half2 hp;
        hp.x = __float2half_rn(ALPHA * o0);
        hp.y = __float2half_rn(ALPHA * o1);
        gh_out[(size_t)n * 16 + f] = *(unsigned int*)&hp;
    } else {
        float2 wl = ((const float2*)w_last)[f];
        float t = h0 * wl.x + h1 * wl.y;
        #pragma unroll
        for (int m = 8; m >= 1; m >>= 1) t += __shfl_xor(t, m, 16);
        if (f == 0) g1_out[n] = ALPHA * t;
    }
}

// Fused last layer (F=1): out = sigmoid(0.1*x0@WiL@WxL + A@g1)   (g1 is 2 MB, L2-resident)
__global__ void last_fused(const int* __restrict__ rp, const int2* __restrict__ es,
                           const float* __restrict__ g1, const float* __restrict__ x0,
                           const float* __restrict__ wcL, float* __restrict__ out) {
    int tid = blockIdx.x * 256 + threadIdx.x;
    int n = tid >> 5, f = tid & 31;
    if (n >= NN) return;
    int s = (n == 0) ? 0 : rp[n - 1];
    int e_end = rp[n];
    float acc = 0.f;
    for (int e = s + f; e < e_end; e += 32) {
        int2 ev = es[e];
        acc += __int_as_float(ev.y) * g1[ev.x];
    }
    #pragma unroll
    for (int m = 16; m >= 1; m >>= 1) acc += __shfl_xor(acc, m, 32);
    if (f == 0) {
        float z = x0[n * 3 + 0] * wcL[0] + x0[n * 3 + 1] * wcL[1] + x0[n * 3 + 2] * wcL[2] + acc;
        out[n] = 1.f / (1.f + __expf(-z));
    }
}

// ---------------------------------------------------------------------------
// Fallback path (atomic version) for small ws_size — unchanged, known-correct.
__global__ void fb_spmm_f3(const int* __restrict__ rows, const int* __restrict__ cols,
                           const float* __restrict__ vals, const float* __restrict__ x,
                           float* __restrict__ agg3) {
    int e = blockIdx.x * blockDim.x + threadIdx.x;
    if (e >= NE) return;
    int r = rows[e], c = cols[e];
    float v = vals[e];
    atomicAdd(&agg3[r * 3 + 0], v * x[c * 3 + 0]);
    atomicAdd(&agg3[r * 3 + 1], v * x[c * 3 + 1]);
    atomicAdd(&agg3[r * 3 + 2], v * x[c * 3 + 2]);
}
__global__ void fb_epilogue1(const float* __restrict__ agg3, const float* __restrict__ x0,
                             const float* __restrict__ w_init0, const float* __restrict__ w_x0,
                             const float* __restrict__ w_x_next, float* __restrict__ g_out) {
    int tid = blockIdx.x * blockDim.x + threadIdx.x;
    int n = tid >> 5, f = tid & 31;
    if (n >= NN) return;
    float a0 = agg3[n * 3 + 0], a1 = agg3[n * 3 + 1], a2 = agg3[n * 3 + 2];
    float p0 = x0[n * 3 + 0], p1 = x0[n * 3 + 1], p2 = x0[n * 3 + 2];
    float b0 = ALPHA * a0 + OMA * (p0 * w_init0[0] + p1 * w_init0[3] + p2 * w_init0[6]);
    float b1 = ALPHA * a1 + OMA * (p0 * w_init0[1] + p1 * w_init0[4] + p2 * w_init0[7]);
    float b2 = ALPHA * a2 + OMA * (p0 * w_init0[2] + p1 * w_init0[5] + p2 * w_init0[8]);
    float h = fmaxf(b0 * w_x0[f] + b1 * w_x0[HD + f] + b2 * w_x0[2 * HD + f], 0.f);
    float acc = 0.f;
    #pragma unroll
    for (int k = 0; k < HD; ++k) acc += __shfl(h, k, 32) * w_x_next[k * HD + f];
    g_out[n * HD + f] = ALPHA * acc;
}
__global__ void fb_seed_mid(const float* __restrict__ x0, const float* __restrict__ wc,
                            float* __restrict__ agg) {
    int tid = blockIdx.x * blockDim.x + threadIdx.x;
    int n = tid >> 5, f = tid & 31;
    if (n >= NN) return;
    agg[n * HD + f] = x0[n * 3 + 0] * wc[f] + x0[n * 3 + 1] * wc[HD + f] + x0[n * 3 + 2] * wc[2 * HD + f];
}
__global__ void fb_spmm_f32(const int* __restrict__ rows, const int* __restrict__ cols,
                            const float* __restrict__ vals, const float* __restrict__ g,
                            float* __restrict__ agg) {
    int tid = blockIdx.x * blockDim.x + threadIdx.x;
    int e = tid >> 5, f = tid & 31;
    if (e >= NE) return;
    atomicAdd(&agg[rows[e] * HD + f], vals[e] * g[cols[e] * HD + f]);
}
__global__ void fb_epilogue_mid(const float* __restrict__ agg, const float* __restrict__ w_x_next,
                                float* __restrict__ g_out) {
    int tid = blockIdx.x * blockDim.x + threadIdx.x;
    int n = tid >> 5, f = tid & 31;
    if (n >= NN) return;
    float h = fmaxf(agg[n * HD + f], 0.f);
    float acc = 0.f;
    #pragma unroll
    for (int k = 0; k < HD; ++k) acc += __shfl(h, k, 32) * w_x_next[k * HD + f];
    g_out[n * HD + f] = ALPHA * acc;
}
__global__ void fb_epilogue_to1(const float* __restrict__ agg, const float* __restrict__ w_x_last,
                                float* __restrict__ g1) {
    int tid = blockIdx.x * blockDim.x + threadIdx.x;
    int n = tid >> 5, f = tid & 31;
    if (n >= NN) return;
    float v = fmaxf(agg[n * HD + f], 0.f) * w_x_last[f];
    #pragma unroll
    for (int m = 16; m >= 1; m >>= 1) v += __shfl_xor(v, m, 32);
    if (f == 0) g1[n] = ALPHA * v;
}
__global__ void fb_seed_last(const float* __restrict__ x0, const float* __restrict__ wcL,
                             float* __restrict__ aggL) {
    int n = blockIdx.x * blockDim.x + threadIdx.x;
    if (n >= NN) return;
    aggL[n] = x0[n * 3 + 0] * wcL[0] + x0[n * 3 + 1] * wcL[1] + x0[n * 3 + 2] * wcL[2];
}
__global__ void fb_spmm_f1(const int* __restrict__ rows, const int* __restrict__ cols,
                           const float* __restrict__ vals, const float* __restrict__ g1,
                           float* __restrict__ aggL) {
    int e = blockIdx.x * blockDim.x + threadIdx.x;
    if (e >= NE) return;
    atomicAdd(&aggL[rows[e]], vals[e] * g1[cols[e]]);
}
__global__ void fb_final_sigmoid(const float* __restrict__ aggL, float* __restrict__ out) {
    int n = blockIdx.x * blockDim.x + threadIdx.x;
    if (n >= NN) return;
    out[n] = 1.f / (1.f + __expf(-aggL[n]));
}
__global__ void fb_prep_weights(const float* __restrict__ w_init_mid,
                                const float* __restrict__ w_x_mid,
                                const float* __restrict__ w_init_last,
                                const float* __restrict__ w_x_last,
                                float* __restrict__ wc_mid,
                                float* __restrict__ wc_last) {
    int t = threadIdx.x;
    if (t < NMID * F0 * HD) {
        int i = t / (F0 * HD);
        int r = t - i * (F0 * HD);
        int k = r / HD, f = r % HD;
        const float* wi = w_init_mid + (size_t)i * F0 * HD;
        const float* wx = w_x_mid + (size_t)i * HD * HD;
        float acc = 0.f;
        for (int j = 0; j < HD; ++j) acc += wi[k * HD + j] * wx[j * HD + f];
        wc_mid[t] = OMA * acc;
    } else if (t < NMID * F0 * HD + F0) {
        int k = t - NMID * F0 * HD;
        float acc = 0.f;
        for (int j = 0; j < HD; ++j) acc += w_init_last[k * HD + j] * w_x_last[j];
        wc_last[k] = OMA * acc;
    }
}

// ---------------------------------------------------------------------------
extern "C" void kernel_launch(void* const* d_in, const int* in_sizes, int n_in,
                              void* d_out, int out_size, void* d_ws, size_t ws_size,
                              hipStream_t stream) {
    const float* x           = (const float*)d_in[0];
    const int*   rows        = (const int*)d_in[1];
    const int*   cols        = (const int*)d_in[2];
    const float* vals        = (const float*)d_in[3];
    const float* w_init0     = (const float*)d_in[4];
    const float* w_x0        = (const float*)d_in[5];
    const float* w_init_mid  = (const float*)d_in[6];
    const float* w_x_mid     = (const float*)d_in[7];
    const float* w_init_last = (const float*)d_in[8];
    const float* w_x_last    = (const float*)d_in[9];
    float* out = (float*)d_out;

    const int B = 256;
    const int gridE   = NE / B;
    const int gridN32 = (NN * 32 + B - 1) / B;
    const int gridN16 = (NN * 16 + B - 1) / B;
    const int gridN   = (NN + B - 1) / B;

    const size_t SZ_ES = (size_t)NE * 8;      // 128e6 packed edges
    const size_t SZ_G  = (size_t)NN * HD * 4; // 64e6 (layout constant from round 2)
    const size_t SZ_RP = (size_t)NN * 4;      // 2e6
    const size_t NEED  = SZ_ES + 2 * SZ_G + SZ_RP + 4096 + 4096; // same guarantee as round 2/3

    if (ws_size >= NEED) {
        char* base = (char*)d_ws;
        int2*  es   = (int2*)base;                       // [0, 128e6)
        char*  reg2 = base + SZ_ES;                      // [128e6, 256e6): tmp during build
        int2*  tmp  = (int2*)reg2;                       //   build-only, 128e6
        unsigned int* gA = (unsigned int*)reg2;          //   [ +0,   +32e6): fp16 g ping
        unsigned int* gB = (unsigned int*)(reg2 + (size_t)NN * HD * 2);   // [ +32e6, +64e6)
        float* g1   = (float*)(reg2 + (size_t)2 * NN * HD * 2);           // [ +64e6, +66e6)
        float4* wpk = (float4*)(reg2 + 70000000);        //   packed weights (post-build)
        float2* wc2 = (float2*)(reg2 + 70000000 + 5 * 256 * 16);
        float*  wcl = (float*)(reg2 + 70000000 + 5 * 256 * 16 + NMID * 48 * 8);
        int*   rp   = (int*)(base + SZ_ES + 2 * SZ_G);   // [256e6, 258e6)
        int*   bkt  = (int*)(base + SZ_ES + 2 * SZ_G + SZ_RP); // 4 KB

        // ---- build CSR ----
        hipMemsetAsync(bkt, 0, NBUK * sizeof(int), stream);
        bucket_hist<<<GRID_P, 512, 0, stream>>>(rows, bkt);
        scan_buckets<<<1, 512, 0, stream>>>(bkt);
        p1_scatter<<<GRID_P, 512, 0, stream>>>(rows, cols, vals, bkt, tmp);
        p2_csr<<<NBUK, RPB, 0, stream>>>(bkt, tmp, rp, es);

        // ---- pack weights (tmp is dead now) ----
        prep_pack<<<4, 512, 0, stream>>>(w_init_mid, w_x_mid, w_init_last, w_x_last,
                                         wpk, wc2, wcl);

        // ---- layers ----
        layer1_fused<<<gridN32, B, 0, stream>>>(rp, es, x, w_init0, w_x0, w_x_mid, gA);
        unsigned int* gin = gA; unsigned int* gout = gB;
        for (int i = 0; i < NMID - 1; ++i) {
            mid_fused<0><<<gridN16, B, 0, stream>>>(rp, es, gin, x, wc2 + i * 48,
                                                    wpk + i * 256, nullptr, nullptr, gout);
            unsigned int* t = gin; gin = gout; gout = t;
        }
        mid_fused<1><<<gridN16, B, 0, stream>>>(rp, es, gin, x, wc2 + 5 * 48,
                                                nullptr, w_x_last, g1, nullptr);
        last_fused<<<gridN32, B, 0, stream>>>(rp, es, g1, x, wcl, out);
    } else {
        // -------- fallback: atomic path --------
        char* ws = (char*)d_ws;
        float* g      = (float*)ws;
        float* agg    = (float*)(ws + SZ_G);
        float* wc_mid = (float*)(ws + 2 * SZ_G);
        float* wc_last = wc_mid + NMID * F0 * HD;

        fb_prep_weights<<<1, 1024, 0, stream>>>(w_init_mid, w_x_mid, w_init_last, w_x_last,
                                                wc_mid, wc_last);
        hipMemsetAsync(agg, 0, (size_t)NN * 3 * sizeof(float), stream);
        fb_spmm_f3<<<gridE, B, 0, stream>>>(rows, cols, vals, x, agg);
        fb_epilogue1<<<gridN32, B, 0, stream>>>(agg, x, w_init0, w_x0, w_x_mid, g);
        const int gridE32 = (int)(((size_t)NE * 32) / B);
        for (int i = 0; i < NMID; ++i) {
            fb_seed_mid<<<gridN32, B, 0, stream>>>(x, wc_mid + i * F0 * HD, agg);
            fb_spmm_f32<<<gridE32, B, 0, stream>>>(rows, cols, vals, g, agg);
            if (i < NMID - 1)
                fb_epilogue_mid<<<gridN32, B, 0, stream>>>(agg, w_x_mid + (size_t)(i + 1) * HD * HD, g);
            else
                fb_epilogue_to1<<<gridN32, B, 0, stream>>>(agg, w_x_last, g);
        }
        fb_seed_last<<<gridN, B, 0, stream>>>(x, wc_last, agg);
        fb_spmm_f1<<<gridE, B, 0, stream>>>(rows, cols, vals, g, agg);
        fb_final_sigmoid<<<gridN, B, 0, stream>>>(agg, out);
    }
}